// Round 8
// baseline (10515.568 us; speedup 1.0000x reference)
//
#include <hip/hip_runtime.h>
#include <stdint.h>

// RTRBM CD-1: bit-exact replication of the JAX-CPU reference.
// Recurrence is independent per batch column -> no grid sync ever.
// Phase A: WV2[bg][t][h][2] = W @ v_t (FMA exact: v binary), into out_v region.
// Phase B: hidden_cols — 128 blocks x 1024 threads (2 cols/block, k-panel split
//          across thread halves at the Eigen kc=288 boundary), r in LDS,
//          U float4-streamed from L2, h out as ballot-packed bits (in d_ws).
// Phase E: expand bits -> out_r floats.
// Phase C: all visible steps, one launch, h read as PACKED BITS (FMA exact).
// Sizes: V=784, H=500, T=256, B=256. RNG: threefry partitionable.
// Eigen MT blocking (AVX no-FMA jaxlib): kc=288. K=784 -> [288,288,208]; K=500 -> [288,212].
#define NV 784
#define NH 500
#define TT 256
#define BB 256
#define NBG 128   // b-pairs

// ---------------- threefry2x32 (JAX PRNG), exact ----------------
__device__ __forceinline__ void tf2x32(uint32_t ks0, uint32_t ks1,
                                       uint32_t x0, uint32_t x1,
                                       uint32_t& y0, uint32_t& y1) {
  uint32_t ks2 = ks0 ^ ks1 ^ 0x1BD11BDAu;
  x0 += ks0; x1 += ks1;
#define TFROT(r) { x0 += x1; x1 = (x1 << (r)) | (x1 >> (32 - (r))); x1 ^= x0; }
  TFROT(13) TFROT(15) TFROT(26) TFROT(6)
  x0 += ks1; x1 += ks2 + 1u;
  TFROT(17) TFROT(29) TFROT(16) TFROT(24)
  x0 += ks2; x1 += ks0 + 2u;
  TFROT(13) TFROT(15) TFROT(26) TFROT(6)
  x0 += ks0; x1 += ks1 + 3u;
  TFROT(17) TFROT(29) TFROT(16) TFROT(24)
  x0 += ks1; x1 += ks2 + 4u;
  TFROT(13) TFROT(15) TFROT(26) TFROT(6)
  x0 += ks2; x1 += ks0 + 5u;
#undef TFROT
  y0 = x0; y1 = x1;
}

__device__ __forceinline__ float jax_uniform(uint32_t bits) {
#pragma clang fp contract(off)
  float f = __uint_as_float((bits >> 9) | 0x3F800000u);
  return f - 1.0f;
}

// PARTITIONABLE random_bits, 32-bit: bits[j] = y0 ^ y1 of threefry(key; 0, j)
__device__ __forceinline__ uint32_t draw_bits(uint32_t k0, uint32_t k1,
                                              uint32_t j) {
  uint32_t y0, y1;
  tf2x32(k0, k1, 0u, j, y0, y1);
  return y0 ^ y1;
}

// ---------------- XLA CPU exp (Cephes/Eigen poly, no FMA) ----------------
__device__ __forceinline__ float xla_expf(float x) {
#pragma clang fp contract(off)
  float xc = fminf(fmaxf(x, -88.3762626647949f), 88.3762626647950f);
  float fx = floorf(xc * 1.44269504088896341f + 0.5f);
  float tmp = 0.693359375f * fx;
  float z = -2.12194440e-4f * fx;
  float xr = xc - tmp;
  xr = xr - z;
  z = xr * xr;
  float y = xr * 1.9875691500e-4f + 1.3981999507e-3f;
  y = y * xr + 8.3334519073e-3f;
  y = y * xr + 4.1665795894e-2f;
  y = y * xr + 1.6666665459e-1f;
  y = y * xr + 5.0000001201e-1f;
  y = y * z + xr;
  y = 1.0f + y;
  int e = (int)fx;
  float pow2 = __int_as_float((uint32_t)(e + 127) << 23);
  return y * pow2;
}

__device__ __forceinline__ float xla_sigmoid(float x) {
#pragma clang fp contract(off)
  float e = xla_expf(-x);
  float d = 1.0f + e;
  return 1.0f / d;
}

// ---------------- key derivation (PARTITIONABLE split) ----------------
__global__ void init_keys(uint32_t* __restrict__ keys /* [256][4] */) {
  int t = threadIdx.x;
  if (t >= TT) return;
  uint32_t kt0, kt1;
  tf2x32(0u, 123u, 0u, (uint32_t)t, kt0, kt1);
  uint32_t a0, a1, b0, b1;
  tf2x32(kt0, kt1, 0u, 0u, a0, a1);  // k1 (hidden)
  tf2x32(kt0, kt1, 0u, 1u, b0, b1);  // k2 (visible)
  keys[4 * t + 0] = a0;
  keys[4 * t + 1] = a1;
  keys[4 * t + 2] = b0;
  keys[4 * t + 3] = b1;
}

// ---------------- W transpose: WT[i][k] = W[k][i] ----------------
__global__ __launch_bounds__(256) void wt_kernel(const float* __restrict__ W,
                                                 float* __restrict__ WT) {
  const int i = blockIdx.x;           // 0..783
  for (int k = threadIdx.x; k < NH; k += 256)
    WT[(size_t)i * NH + k] = W[(size_t)k * NV + i];
}

// ---------------- Phase A: WV2[bg][t][h][2] = (W @ v_t)[h][b] ----------------
// fmaf(w, x, s) == s + w*x bit-exactly because x in {0,1} (w*x exact).
#define HT_A 25   // 500/25 = 20 blocks per t
__global__ __launch_bounds__(256) void wv_gemm(
    const float* __restrict__ v, const float* __restrict__ W,
    float* __restrict__ wv2) {
#pragma clang fp contract(off)
  const int b = threadIdx.x;
  const int h0 = blockIdx.x * HT_A;
  const int t = blockIdx.y;
  const float* vcol = v + (size_t)t * BB + b;   // element k: vcol[k * TT*BB]

  float acc[HT_A];
#pragma unroll
  for (int r = 0; r < HT_A; ++r) acc[r] = 0.0f;

  const int pb[4] = {0, 288, 576, 784};   // kc=288 panels
#pragma unroll 1
  for (int p = 0; p < 3; ++p) {
    float ps[HT_A];
#pragma unroll
    for (int r = 0; r < HT_A; ++r) ps[r] = 0.0f;
    const int k0 = pb[p], k1 = pb[p + 1];
#pragma unroll 16
    for (int k = k0; k < k1; ++k) {
      float x = vcol[(size_t)k * (TT * BB)];
#pragma unroll
      for (int r = 0; r < HT_A; ++r)
        ps[r] = __builtin_fmaf(W[(size_t)(h0 + r) * NV + k], x, ps[r]);
    }
#pragma unroll
    for (int r = 0; r < HT_A; ++r) acc[r] = acc[r] + ps[r];
  }

  // LDS transpose so stores are h-contiguous runs of 50 floats per bg
  __shared__ float al[HT_A][BB];
#pragma unroll
  for (int r = 0; r < HT_A; ++r) al[r][b] = acc[r];
  __syncthreads();

  // write 50-float runs: wv2[bg][t][h0*2 .. h0*2+49]
  const int tid = b;
  const int sub = tid / 50;       // 0..4 (5 bg per iter), tid<250 active
  const int idx = tid % 50;       // h = h0 + idx/2, j = idx&1
#pragma unroll 1
  for (int it = 0; it < 26; ++it) {
    const int bg = it * 5 + sub;
    if (tid < 250 && bg < NBG) {
      wv2[((size_t)bg * TT + t) * 1024 + h0 * 2 + idx] =
          al[idx >> 1][2 * bg + (idx & 1)];
    }
  }
}

// ---------------- Phase B: per-b-pair recurrence, panel-split threads ----------------
// 1024 threads: tid 0-511 = panel 0 (k 0..287 + epilogue), 512-1023 = panel 1
// (k 288..499 + RNG). acc = pa + ps1 is the reference's (0+panel0)+panel1.
__global__ __launch_bounds__(1024) void hidden_cols(
    const float* __restrict__ U, const float* __restrict__ b_h,
    const float* __restrict__ b_init, const uint32_t* __restrict__ keys,
    const float* __restrict__ wv2, uint32_t* __restrict__ hbw) {
#pragma clang fp contract(off)
  const int tid = threadIdx.x;
  const int pan = tid >> 9;           // wave-uniform
  const int h = tid & 511;
  const int hs = (h < NH) ? h : 0;    // safe row for padding lanes
  const int bg = (int)blockIdx.x;
  const int b0 = 2 * bg;

  __shared__ float rO[2][2][512];     // [buf][col][h] ping-pong
  __shared__ float ps_l[2][512];      // panel-1 partials per col
  __shared__ float u_l[2][512];       // uniforms per col
  __shared__ uint32_t keyl[2 * TT];

  if (tid < 2 * TT) keyl[tid] = keys[4 * (tid >> 1) + (tid & 1)];
  if (pan == 0) { rO[0][0][h] = 0.0f; rO[0][1][h] = 0.0f; }  // r_lag(0)=0
  const float bh = b_h[hs], bi = b_init[hs];
  const float* __restrict__ Urow = U + (size_t)hs * NH + (pan ? 288 : 0);
  __syncthreads();

#pragma unroll 1
  for (int t = 0; t < TT; ++t) {
    const int cur = t & 1, nx = cur ^ 1;

    float2 wvp; wvp.x = 0.0f; wvp.y = 0.0f;
    if (pan == 0)   // prefetch epilogue operand (coalesced 8B/lane)
      wvp = *(const float2*)&wv2[((size_t)bg * TT + t) * 1024 + h * 2];

    const float* __restrict__ ro0 = &rO[cur][0][pan ? 288 : 0];
    const float* __restrict__ ro1 = &rO[cur][1][pan ? 288 : 0];

    // mul-then-add (no FMA: r arbitrary), strict ascending k per panel chain
    float pa = 0.0f, pb = 0.0f;
    if (pan == 0) {
#pragma unroll 8
      for (int c = 0; c < 72; ++c) {         // k = 0..287
        const float4 u4 = *(const float4*)(Urow + 4 * c);
        const float4 ra = *(const float4*)(ro0 + 4 * c);
        const float4 rb = *(const float4*)(ro1 + 4 * c);
        pa = pa + u4.x * ra.x; pa = pa + u4.y * ra.y;
        pa = pa + u4.z * ra.z; pa = pa + u4.w * ra.w;
        pb = pb + u4.x * rb.x; pb = pb + u4.y * rb.y;
        pb = pb + u4.z * rb.z; pb = pb + u4.w * rb.w;
      }
    } else {
#pragma unroll 8
      for (int c = 0; c < 53; ++c) {         // k = 288..499
        const float4 u4 = *(const float4*)(Urow + 4 * c);
        const float4 ra = *(const float4*)(ro0 + 4 * c);
        const float4 rb = *(const float4*)(ro1 + 4 * c);
        pa = pa + u4.x * ra.x; pa = pa + u4.y * ra.y;
        pa = pa + u4.z * ra.z; pa = pa + u4.w * ra.w;
        pb = pb + u4.x * rb.x; pb = pb + u4.y * rb.y;
        pb = pb + u4.z * rb.z; pb = pb + u4.w * rb.w;
      }
      ps_l[0][h] = pa;
      ps_l[1][h] = pb;
      const uint32_t k0 = keyl[2 * t], k1 = keyl[2 * t + 1];
      u_l[0][h] = jax_uniform(draw_bits(k0, k1, (uint32_t)(h * BB + b0)));
      u_l[1][h] = jax_uniform(draw_bits(k0, k1, (uint32_t)(h * BB + b0 + 1)));
    }
    __syncthreads();

    if (pan == 0) {
      const float acc0 = pa + ps_l[0][h];    // == (0+panel0)+panel1
      const float acc1 = pb + ps_l[1][h];
      const float bias = (t == 0) ? bi : bh;
      const float pre0 = (wvp.x + acc0) + bias;   // reference order
      const float pre1 = (wvp.y + acc1) + bias;
      const float pp0 = xla_sigmoid(pre0);
      const float pp1 = xla_sigmoid(pre1);
      rO[nx][0][h] = pp0;
      rO[nx][1][h] = pp1;
      const bool hm0 = u_l[0][h] < pp0;
      const bool hm1 = u_l[1][h] < pp1;
      const unsigned long long m0 = __ballot(hm0);
      const unsigned long long m1 = __ballot(hm1);
      const int lh = h & 63;
      if (lh == 0) {
        uint2 w; w.x = (uint32_t)m0; w.y = (uint32_t)m1;
        *(uint2*)&hbw[(size_t)(h >> 5) * (TT * BB) + (size_t)t * BB + b0] = w;
      }
      if (lh == 32) {
        uint2 w; w.x = (uint32_t)(m0 >> 32); w.y = (uint32_t)(m1 >> 32);
        *(uint2*)&hbw[(size_t)(h >> 5) * (TT * BB) + (size_t)t * BB + b0] = w;
      }
    }
    __syncthreads();
  }
}

// ---------------- Phase E: expand packed h bits -> out_r floats ----------------
__global__ __launch_bounds__(256) void expand_r(
    const uint32_t* __restrict__ hbw, float* __restrict__ out_r) {
  const int h = blockIdx.x;           // 0..499
  const int b = threadIdx.x;
  const uint32_t sh = (uint32_t)(h & 31);
  const uint32_t* src = hbw + (size_t)(h >> 5) * (TT * BB);
  float* dst = out_r + (size_t)h * (TT * BB);
#pragma unroll 4
  for (int t = 0; t < TT; ++t) {
    uint32_t w = src[t * BB + b];
    dst[t * BB + b] = (float)((w >> sh) & 1u);
  }
}

// ---------------- Phase C: all visible steps from PACKED h bits ----------------
// hh = bit ? 1.0 : 0.0; fmaf(w, hh, s) == s + w*h bit-exactly (h in {0,1}).
#define IT_C 16   // 784/16 = 49 i-tiles
__global__ __launch_bounds__(256) void visible_big(
    const float* __restrict__ WT, const float* __restrict__ b_v,
    const uint32_t* __restrict__ keys, const uint32_t* __restrict__ hbw,
    float* __restrict__ out_v) {
#pragma clang fp contract(off)
  const int b = threadIdx.x;
  const int i0 = blockIdx.x * IT_C;
  const int t = blockIdx.y;
  const uint32_t* __restrict__ hw = hbw + (size_t)t * BB + b;  // word w: hw[w*TT*BB]

  float acc[IT_C];
#pragma unroll
  for (int r = 0; r < IT_C; ++r) acc[r] = 0.0f;

  // Eigen panels at k=288 (word 9 boundary: 288 = 9*32)
#pragma unroll 1
  for (int p = 0; p < 2; ++p) {
    float ps[IT_C];
#pragma unroll
    for (int r = 0; r < IT_C; ++r) ps[r] = 0.0f;
    const int w0 = p ? 9 : 0, w1 = p ? 16 : 9;
#pragma unroll 1
    for (int w = w0; w < w1; ++w) {
      const uint32_t bits = hw[(size_t)w * (TT * BB)];
#pragma unroll 8
      for (int j = 0; j < 32; ++j) {
        const int k = w * 32 + j;
        if (k < NH) {
          const float hh = ((bits >> j) & 1u) ? 1.0f : 0.0f;
#pragma unroll
          for (int r = 0; r < IT_C; ++r)
            ps[r] = __builtin_fmaf(WT[(size_t)(i0 + r) * NH + k], hh, ps[r]);
        }
      }
    }
#pragma unroll
    for (int r = 0; r < IT_C; ++r) acc[r] = acc[r] + ps[r];
  }

  const uint32_t key0 = keys[4 * t + 2], key1 = keys[4 * t + 3];
#pragma unroll
  for (int r = 0; r < IT_C; ++r) {
    const int i = i0 + r;
    float pre = acc[r] + b_v[i];
    float p = xla_sigmoid(pre);
    uint32_t j = (uint32_t)(i * BB + b);
    float u = jax_uniform(draw_bits(key0, key1, j));
    out_v[(size_t)i * (TT * BB) + (size_t)t * BB + b] = (u < p) ? 1.0f : 0.0f;
  }
}

extern "C" void kernel_launch(void* const* d_in, const int* in_sizes, int n_in,
                              void* d_out, int out_size, void* d_ws, size_t ws_size,
                              hipStream_t stream) {
  const float* v      = (const float*)d_in[0];
  const float* W      = (const float*)d_in[1];
  const float* U      = (const float*)d_in[2];
  const float* b_h    = (const float*)d_in[3];
  const float* b_v    = (const float*)d_in[4];
  const float* b_init = (const float*)d_in[5];

  float* out_v = (float*)d_out;                       // (784,256,256) = 205.5 MB
  float* out_r = out_v + (size_t)NV * TT * BB;        // (500,256,256) = 131 MB

  // wv2 staged inside the out_v region (134.2 MB <= 205.5 MB); dead before
  // phase C overwrites out_v.
  float* wv2 = out_v;

  // ws: WT (1.57 MB) + keys (4 KB) + hbw (4.19 MB)  — ws >= 7.2 MB known-good
  float* WT = (float*)d_ws;
  uint32_t* keys = (uint32_t*)(WT + (size_t)NV * NH);
  uint32_t* hbw = keys + TT * 4;   // [16][256][256] u32

  init_keys<<<1, 256, 0, stream>>>(keys);
  wt_kernel<<<NV, 256, 0, stream>>>(W, WT);

  dim3 gA(NH / HT_A, TT);
  wv_gemm<<<gA, 256, 0, stream>>>(v, W, wv2);

  hidden_cols<<<NBG, 1024, 0, stream>>>(U, b_h, b_init, keys, wv2, hbw);

  expand_r<<<NH, 256, 0, stream>>>(hbw, out_r);

  dim3 gC(NV / IT_C, TT);
  visible_big<<<gC, 256, 0, stream>>>(WT, b_v, keys, hbw, out_v);
}

// Round 9
// 8257.075 us; speedup vs baseline: 1.2735x; 1.2735x over previous
//
#include <hip/hip_runtime.h>
#include <stdint.h>

// RTRBM CD-1: bit-exact replication of the JAX-CPU reference.
// Recurrence independent per batch column -> no grid sync.
// Phase A: WV2[bg][t][h][2] = W @ v_t (FMA exact: v binary), into out_v region.
// Phase B: hidden_cols — 128 blocks x 512 threads, thread h does 2 b-columns,
//          U TRANSPOSED+PAIRED (UTP[k/2][h] float2, lane-coalesced), r in LDS
//          interleaved [h][2], packed-f32 accumulators, h out as packed bits.
// Phase E: expand bits -> out_r floats.
// Phase C: all visible steps from out_r floats (round-7 version; faster than
//          bit-unpack variant per round-8 measurement).
// Sizes: V=784, H=500, T=256, B=256. RNG: threefry partitionable.
// Eigen MT blocking (AVX no-FMA jaxlib): kc=288. K=784 -> [288,288,208]; K=500 -> [288,212].
#define NV 784
#define NH 500
#define TT 256
#define BB 256
#define NBG 128   // b-pairs

typedef float f2v __attribute__((ext_vector_type(2)));

// ---------------- threefry2x32 (JAX PRNG), exact ----------------
__device__ __forceinline__ void tf2x32(uint32_t ks0, uint32_t ks1,
                                       uint32_t x0, uint32_t x1,
                                       uint32_t& y0, uint32_t& y1) {
  uint32_t ks2 = ks0 ^ ks1 ^ 0x1BD11BDAu;
  x0 += ks0; x1 += ks1;
#define TFROT(r) { x0 += x1; x1 = (x1 << (r)) | (x1 >> (32 - (r))); x1 ^= x0; }
  TFROT(13) TFROT(15) TFROT(26) TFROT(6)
  x0 += ks1; x1 += ks2 + 1u;
  TFROT(17) TFROT(29) TFROT(16) TFROT(24)
  x0 += ks2; x1 += ks0 + 2u;
  TFROT(13) TFROT(15) TFROT(26) TFROT(6)
  x0 += ks0; x1 += ks1 + 3u;
  TFROT(17) TFROT(29) TFROT(16) TFROT(24)
  x0 += ks1; x1 += ks2 + 4u;
  TFROT(13) TFROT(15) TFROT(26) TFROT(6)
  x0 += ks2; x1 += ks0 + 5u;
#undef TFROT
  y0 = x0; y1 = x1;
}

__device__ __forceinline__ float jax_uniform(uint32_t bits) {
#pragma clang fp contract(off)
  float f = __uint_as_float((bits >> 9) | 0x3F800000u);
  return f - 1.0f;
}

// PARTITIONABLE random_bits, 32-bit: bits[j] = y0 ^ y1 of threefry(key; 0, j)
__device__ __forceinline__ uint32_t draw_bits(uint32_t k0, uint32_t k1,
                                              uint32_t j) {
  uint32_t y0, y1;
  tf2x32(k0, k1, 0u, j, y0, y1);
  return y0 ^ y1;
}

// ---------------- XLA CPU exp (Cephes/Eigen poly, no FMA) ----------------
__device__ __forceinline__ float xla_expf(float x) {
#pragma clang fp contract(off)
  float xc = fminf(fmaxf(x, -88.3762626647949f), 88.3762626647950f);
  float fx = floorf(xc * 1.44269504088896341f + 0.5f);
  float tmp = 0.693359375f * fx;
  float z = -2.12194440e-4f * fx;
  float xr = xc - tmp;
  xr = xr - z;
  z = xr * xr;
  float y = xr * 1.9875691500e-4f + 1.3981999507e-3f;
  y = y * xr + 8.3334519073e-3f;
  y = y * xr + 4.1665795894e-2f;
  y = y * xr + 1.6666665459e-1f;
  y = y * xr + 5.0000001201e-1f;
  y = y * z + xr;
  y = 1.0f + y;
  int e = (int)fx;
  float pow2 = __int_as_float((uint32_t)(e + 127) << 23);
  return y * pow2;
}

__device__ __forceinline__ float xla_sigmoid(float x) {
#pragma clang fp contract(off)
  float e = xla_expf(-x);
  float d = 1.0f + e;
  return 1.0f / d;
}

// ---------------- key derivation (PARTITIONABLE split) ----------------
__global__ void init_keys(uint32_t* __restrict__ keys /* [256][4] */) {
  int t = threadIdx.x;
  if (t >= TT) return;
  uint32_t kt0, kt1;
  tf2x32(0u, 123u, 0u, (uint32_t)t, kt0, kt1);
  uint32_t a0, a1, b0, b1;
  tf2x32(kt0, kt1, 0u, 0u, a0, a1);  // k1 (hidden)
  tf2x32(kt0, kt1, 0u, 1u, b0, b1);  // k2 (visible)
  keys[4 * t + 0] = a0;
  keys[4 * t + 1] = a1;
  keys[4 * t + 2] = b0;
  keys[4 * t + 3] = b1;
}

// ---------------- W transpose: WT[i][k] = W[k][i] ----------------
__global__ __launch_bounds__(256) void wt_kernel(const float* __restrict__ W,
                                                 float* __restrict__ WT) {
  const int i = blockIdx.x;           // 0..783
  for (int k = threadIdx.x; k < NH; k += 256)
    WT[(size_t)i * NH + k] = W[(size_t)k * NV + i];
}

// ---------------- U transpose+pair: UTP[p][h] = (U[h][2p], U[h][2p+1]) ----------------
__global__ __launch_bounds__(512) void ut_kernel(const float* __restrict__ U,
                                                 float2* __restrict__ UTP) {
  const int p = blockIdx.x;           // 0..249
  const int h = threadIdx.x;          // 0..511
  float2 w;
  if (h < NH) {
    w.x = U[(size_t)h * NH + 2 * p];
    w.y = U[(size_t)h * NH + 2 * p + 1];
  } else {
    w.x = 0.0f; w.y = 0.0f;
  }
  UTP[(size_t)p * 512 + h] = w;
}

// ---------------- Phase A: WV2[bg][t][h][2] = (W @ v_t)[h][b] ----------------
// fmaf(w, x, s) == s + w*x bit-exactly because x in {0,1} (w*x exact).
#define HT_A 25   // 500/25 = 20 blocks per t
__global__ __launch_bounds__(256) void wv_gemm(
    const float* __restrict__ v, const float* __restrict__ W,
    float* __restrict__ wv2) {
#pragma clang fp contract(off)
  const int b = threadIdx.x;
  const int h0 = blockIdx.x * HT_A;
  const int t = blockIdx.y;
  const float* vcol = v + (size_t)t * BB + b;   // element k: vcol[k * TT*BB]

  float acc[HT_A];
#pragma unroll
  for (int r = 0; r < HT_A; ++r) acc[r] = 0.0f;

  const int pb[4] = {0, 288, 576, 784};   // kc=288 panels
#pragma unroll 1
  for (int p = 0; p < 3; ++p) {
    float ps[HT_A];
#pragma unroll
    for (int r = 0; r < HT_A; ++r) ps[r] = 0.0f;
    const int k0 = pb[p], k1 = pb[p + 1];
#pragma unroll 16
    for (int k = k0; k < k1; ++k) {
      float x = vcol[(size_t)k * (TT * BB)];
#pragma unroll
      for (int r = 0; r < HT_A; ++r)
        ps[r] = __builtin_fmaf(W[(size_t)(h0 + r) * NV + k], x, ps[r]);
    }
#pragma unroll
    for (int r = 0; r < HT_A; ++r) acc[r] = acc[r] + ps[r];
  }

  // LDS transpose so stores are h-contiguous runs of 50 floats per bg
  __shared__ float al[HT_A][BB];
#pragma unroll
  for (int r = 0; r < HT_A; ++r) al[r][b] = acc[r];
  __syncthreads();

  // write 50-float runs: wv2[bg][t][h0*2 .. h0*2+49]
  const int tid = b;
  const int sub = tid / 50;       // 0..4 (5 bg per iter), tid<250 active
  const int idx = tid % 50;       // h = h0 + idx/2, j = idx&1
#pragma unroll 1
  for (int it = 0; it < 26; ++it) {
    const int bg = it * 5 + sub;
    if (tid < 250 && bg < NBG) {
      wv2[((size_t)bg * TT + t) * 1024 + h0 * 2 + idx] =
          al[idx >> 1][2 * bg + (idx & 1)];
    }
  }
}

// ---------------- Phase B: per-b-pair recurrence, coalesced UTP ----------------
// 512 threads; thread h computes both columns over full k. Panels sequential
// in-thread (k 0..287 then 288..499), strict ascending k, mul-then-add:
// exactly the reference chain. acc = a0 + a1 == (0+panel0)+panel1 (-0-safe:
// shown equivalent through the (wv+acc)+bias epilogue).
__global__ __launch_bounds__(512) void hidden_cols(
    const float2* __restrict__ UTP, const float* __restrict__ b_h,
    const float* __restrict__ b_init, const uint32_t* __restrict__ keys,
    const float* __restrict__ wv2, uint32_t* __restrict__ hbw) {
#pragma clang fp contract(off)
  const int h = threadIdx.x;          // 0..511 (500 active)
  const int hs = (h < NH) ? h : 0;
  const int bg = (int)blockIdx.x;
  const int b0 = 2 * bg;

  __shared__ f2v rA[512];             // r ping-pong, interleaved [h] -> (col0,col1)
  __shared__ f2v rB[512];
  __shared__ uint32_t keyl[2 * TT];

  keyl[h] = keys[4 * (h >> 1) + (h & 1)];   // hidden k1 pairs for all t
  {
    f2v z; z.x = 0.0f; z.y = 0.0f;
    rA[h] = z;                               // r_lag(0) = 0
  }
  const float bh = b_h[hs], bi = b_init[hs];
  __syncthreads();

#pragma unroll 1
  for (int t = 0; t < TT; ++t) {
    const f2v* __restrict__ ro = (t & 1) ? rB : rA;
    f2v* __restrict__ rn = (t & 1) ? rA : rB;

    // epilogue operand prefetch (8B/lane, contiguous 4KB per block)
    const f2v wvp = *(const f2v*)&wv2[((size_t)bg * TT + t) * 1024 + h * 2];

    // panel 0: k = 0..287 (pairs 0..143)
    f2v a0; a0.x = 0.0f; a0.y = 0.0f;
#pragma unroll 8
    for (int p = 0; p < 144; ++p) {
      const float2 u2 = UTP[(size_t)p * 512 + h];   // coalesced
      const f2v r0 = ro[2 * p];                     // LDS broadcast
      const f2v r1 = ro[2 * p + 1];
      f2v ux; ux.x = u2.x; ux.y = u2.x;
      f2v uy; uy.x = u2.y; uy.y = u2.y;
      a0 = a0 + ux * r0;     // mul-then-add (contract off): both cols packed
      a0 = a0 + uy * r1;
    }
    // panel 1: k = 288..499 (pairs 144..249)
    f2v a1; a1.x = 0.0f; a1.y = 0.0f;
#pragma unroll 8
    for (int p = 144; p < 250; ++p) {
      const float2 u2 = UTP[(size_t)p * 512 + h];
      const f2v r0 = ro[2 * p];
      const f2v r1 = ro[2 * p + 1];
      f2v ux; ux.x = u2.x; ux.y = u2.x;
      f2v uy; uy.x = u2.y; uy.y = u2.y;
      a1 = a1 + ux * r0;
      a1 = a1 + uy * r1;
    }

    const f2v acc = a0 + a1;            // == (0+panel0)+panel1
    const float bias = (t == 0) ? bi : bh;
    const float pre0 = (wvp.x + acc.x) + bias;   // reference order
    const float pre1 = (wvp.y + acc.y) + bias;
    const float pp0 = xla_sigmoid(pre0);
    const float pp1 = xla_sigmoid(pre1);

    const uint32_t key0 = keyl[2 * t], key1 = keyl[2 * t + 1];
    const float u0 = jax_uniform(draw_bits(key0, key1, (uint32_t)(h * BB + b0)));
    const float u1 = jax_uniform(draw_bits(key0, key1, (uint32_t)(h * BB + b0 + 1)));
    const bool hm0 = u0 < pp0;
    const bool hm1 = u1 < pp1;

    // pack h samples: 64-lane ballot over h within the wave
    const unsigned long long m0 = __ballot(hm0);
    const unsigned long long m1 = __ballot(hm1);
    const int lh = h & 63;
    if (lh == 0) {
      uint2 w; w.x = (uint32_t)m0; w.y = (uint32_t)m1;
      *(uint2*)&hbw[(size_t)(h >> 5) * (TT * BB) + (size_t)t * BB + b0] = w;
    }
    if (lh == 32) {
      uint2 w; w.x = (uint32_t)(m0 >> 32); w.y = (uint32_t)(m1 >> 32);
      *(uint2*)&hbw[(size_t)(h >> 5) * (TT * BB) + (size_t)t * BB + b0] = w;
    }

    f2v pv; pv.x = pp0; pv.y = pp1;
    rn[h] = pv;
    __syncthreads();
  }
}

// ---------------- Phase E: expand packed h bits -> out_r floats ----------------
__global__ __launch_bounds__(256) void expand_r(
    const uint32_t* __restrict__ hbw, float* __restrict__ out_r) {
  const int h = blockIdx.x;           // 0..499
  const int b = threadIdx.x;
  const uint32_t sh = (uint32_t)(h & 31);
  const uint32_t* src = hbw + (size_t)(h >> 5) * (TT * BB);
  float* dst = out_r + (size_t)h * (TT * BB);
#pragma unroll 4
  for (int t = 0; t < TT; ++t) {
    uint32_t w = src[t * BB + b];
    dst[t * BB + b] = (float)((w >> sh) & 1u);
  }
}

// ---------------- Phase C: all visible steps; h read from out_r ----------------
// fmaf(w, h, s) == s + w*h bit-exactly because h in {0,1}.
#define IT_C 16   // 784/16 = 49 i-tiles
__global__ __launch_bounds__(256) void visible_big(
    const float* __restrict__ WT, const float* __restrict__ b_v,
    const uint32_t* __restrict__ keys, const float* __restrict__ hplane,
    float* __restrict__ out_v) {
#pragma clang fp contract(off)
  const int b = threadIdx.x;
  const int i0 = blockIdx.x * IT_C;
  const int t = blockIdx.y;
  const float* hcol = hplane + (size_t)t * BB + b;  // element k: hcol[k * TT*BB]

  float acc[IT_C];
#pragma unroll
  for (int r = 0; r < IT_C; ++r) acc[r] = 0.0f;

  const int pb[3] = {0, 288, 500};
#pragma unroll 1
  for (int p = 0; p < 2; ++p) {
    float ps[IT_C];
#pragma unroll
    for (int r = 0; r < IT_C; ++r) ps[r] = 0.0f;
    const int k0 = pb[p], k1 = pb[p + 1];
#pragma unroll 8
    for (int k = k0; k < k1; ++k) {
      float hh = hcol[(size_t)k * (TT * BB)];
#pragma unroll
      for (int r = 0; r < IT_C; ++r)
        ps[r] = __builtin_fmaf(WT[(size_t)(i0 + r) * NH + k], hh, ps[r]);
    }
#pragma unroll
    for (int r = 0; r < IT_C; ++r) acc[r] = acc[r] + ps[r];
  }

  const uint32_t key0 = keys[4 * t + 2], key1 = keys[4 * t + 3];
#pragma unroll
  for (int r = 0; r < IT_C; ++r) {
    const int i = i0 + r;
    float pre = acc[r] + b_v[i];
    float p = xla_sigmoid(pre);
    uint32_t j = (uint32_t)(i * BB + b);
    float u = jax_uniform(draw_bits(key0, key1, j));
    out_v[(size_t)i * (TT * BB) + (size_t)t * BB + b] = (u < p) ? 1.0f : 0.0f;
  }
}

extern "C" void kernel_launch(void* const* d_in, const int* in_sizes, int n_in,
                              void* d_out, int out_size, void* d_ws, size_t ws_size,
                              hipStream_t stream) {
  const float* v      = (const float*)d_in[0];
  const float* W      = (const float*)d_in[1];
  const float* U      = (const float*)d_in[2];
  const float* b_h    = (const float*)d_in[3];
  const float* b_v    = (const float*)d_in[4];
  const float* b_init = (const float*)d_in[5];

  float* out_v = (float*)d_out;                       // (784,256,256) = 205.5 MB
  float* out_r = out_v + (size_t)NV * TT * BB;        // (500,256,256) = 131 MB

  // wv2 staged inside the out_v region (134.2 MB <= 205.5 MB); dead before
  // phase C overwrites out_v. UTP staged at the head of the out_r region
  // (1.02 MB); dead before phase E overwrites out_r.
  float* wv2 = out_v;
  float2* UTP = (float2*)out_r;

  // ws: WT (1.57 MB) + keys (4 KB) + hbw (4.19 MB)
  float* WT = (float*)d_ws;
  uint32_t* keys = (uint32_t*)(WT + (size_t)NV * NH);
  uint32_t* hbw = keys + TT * 4;   // [16][256][256] u32

  init_keys<<<1, 256, 0, stream>>>(keys);
  wt_kernel<<<NV, 256, 0, stream>>>(W, WT);
  ut_kernel<<<250, 512, 0, stream>>>(U, UTP);

  dim3 gA(NH / HT_A, TT);
  wv_gemm<<<gA, 256, 0, stream>>>(v, W, wv2);

  hidden_cols<<<NBG, 512, 0, stream>>>(UTP, b_h, b_init, keys, wv2, hbw);

  expand_r<<<NH, 256, 0, stream>>>(hbw, out_r);

  dim3 gC(NV / IT_C, TT);
  visible_big<<<gC, 256, 0, stream>>>(WT, b_v, keys, hbw ? (const float*)out_r : nullptr, out_v);
}